// Round 7
// baseline (1745.211 us; speedup 1.0000x reference)
//
#include <hip/hip_runtime.h>
#include <stdint.h>

#define DD 512
#define KK 4096
#define NN 32768

typedef __attribute__((ext_vector_type(8))) short bf16x8;
typedef __attribute__((ext_vector_type(4))) float f32x4;

__device__ __forceinline__ unsigned short bf16_rn(float f) {
  uint32_t u = __float_as_uint(f);
  return (unsigned short)((u + 0x7FFFu + ((u >> 16) & 1u)) >> 16);
}

// ---- fused prep: blocks [0,2048) do E transpose/bf16/he2; [2048,10240) do x->bf16 ----
// (was two kernels; independent work, one launch, runs concurrently)
template <bool WRITE_ET>
__global__ __launch_bounds__(256) void prep_fused_kernel(
    const float4* __restrict__ x4, unsigned short* __restrict__ xh,
    const float* __restrict__ E, unsigned short* __restrict__ Eth,
    float* __restrict__ he2, float* __restrict__ Et) {
  __shared__ float t[32][33];
  const int bid = blockIdx.x;
  if (bid < 2048) {
    // E prep: transpose + bf16 + he2 (wave-shfl reduce, one atomic per (k,wave))
    int bk = (bid & 127) * 32;
    int bd = (bid >> 7) * 32;
    int c = threadIdx.x & 31;
    int r0 = threadIdx.x >> 5;
#pragma unroll
    for (int r = r0; r < 32; r += 8) t[r][c] = E[(size_t)(bd + r) * KK + bk + c];
    __syncthreads();
#pragma unroll
    for (int i = 0; i < 4; ++i) {
      int r = r0 + i * 8;
      float v = t[c][r];  // = E[(bd+c)*KK + bk+r]  (k = bk+r, d = bd+c)
      size_t o = (size_t)(bk + r) * DD + bd + c;
      Eth[o] = bf16_rn(v);
      if (WRITE_ET) Et[o] = v;
      float v2 = v * v;
#pragma unroll
      for (int m = 1; m < 32; m <<= 1) v2 += __shfl_xor(v2, m, 64);
      if (c == 0) atomicAdd(&he2[bk + r], 0.5f * v2);
    }
  } else {
    // x -> bf16 cast (8 elems/thread)
    int gid = (bid - 2048) * 256 + threadIdx.x;
    float4 a = x4[gid * 2];
    float4 b = x4[gid * 2 + 1];
    union { unsigned short u[8]; uint4 q; } H;
    H.u[0] = bf16_rn(a.x); H.u[1] = bf16_rn(a.y);
    H.u[2] = bf16_rn(a.z); H.u[3] = bf16_rn(a.w);
    H.u[4] = bf16_rn(b.x); H.u[5] = bf16_rn(b.y);
    H.u[6] = bf16_rn(b.z); H.u[7] = bf16_rn(b.w);
    *(uint4*)(xh + (size_t)gid * 8) = H.q;
  }
}

// ---------------- MFMA scores + argmax (R3 kernel, verbatim restore) ----------------
// grid: (NN/128)*8 remapped XCD-aware; block = 128 tokens x 512 codes (4 nt tiles).
// LDS: double-buffered A,B tiles [128][64] bf16 (rows = 128 B), XOR-swizzled chunks:
//   LDS slot (row, pos) holds global 16B-chunk (pos ^ (row&7)).
// Schedule: issue next tile's global_load_lds BEFORE computing the current tile;
// single __syncthreads per step. Measured: 178us, MfmaUtil 33.7, FETCH 92MB, 128 VGPR.
// DO NOT: launch_bounds(256,4) [VGPR->64, spill, R6]; nt-unroll+hv preload [scratch,
// R4]; counted-vmcnt 2-barrier graft [190us, R5].
#define ANB 512
#define BN 128

__device__ __forceinline__ void stage_tile(const unsigned short* __restrict__ xh,
                                           const unsigned short* __restrict__ Eth,
                                           char* Ah, char* Bh, int block_m, int ncode,
                                           int dt, int w, int srow, int schunk) {
#pragma unroll
  for (int r = 0; r < 4; ++r) {
    const int rowbase = w * 32 + r * 8;
    const int arow = block_m + rowbase + srow;
    const int brow = ncode + rowbase + srow;
    const int col = dt + schunk * 8;
    __builtin_amdgcn_global_load_lds(
        (const __attribute__((address_space(1))) void*)(xh + (size_t)arow * DD + col),
        (__attribute__((address_space(3))) void*)(Ah + rowbase * 128), 16, 0, 0);
    __builtin_amdgcn_global_load_lds(
        (const __attribute__((address_space(1))) void*)(Eth + (size_t)brow * DD + col),
        (__attribute__((address_space(3))) void*)(Bh + rowbase * 128), 16, 0, 0);
  }
}

__global__ __launch_bounds__(256, 2) void argmax_mfma_kernel(
    const unsigned short* __restrict__ xh, const unsigned short* __restrict__ Eth,
    const float* __restrict__ he2, unsigned long long* __restrict__ best64) {
  __shared__ __align__(16) char smem[65536];  // 2 x {A[128][64], B[128][64]} bf16

  const int tid = threadIdx.x;
  const int w = tid >> 6;
  const int lane = tid & 63;
  const int wm = w >> 1, wk = w & 1;
  const int l15 = lane & 15, quad = lane >> 4;

  // XCD-aware bijective swizzle: 2048 wgs, 8 XCDs (wg -> XCD = blockIdx%8).
  const int orig = blockIdx.x;
  const int wgid = (orig & 7) * 256 + (orig >> 3);
  const int block_m = (wgid >> 3) * BN;
  const int nbase = (wgid & 7) * ANB;

  const int srow = lane >> 3;                       // 0..7 row within 8-row group
  const int schunk = (lane & 7) ^ (lane >> 3);      // swizzled source chunk
  const int rx = l15 & 7;                           // frag-read xor key

  float best[16];
  int bidx[16];
#pragma unroll
  for (int s = 0; s < 16; ++s) { best[s] = -INFINITY; bidx[s] = 0; }

  // prologue: stage (nt=0, dt=0) into buf 0
  stage_tile(xh, Eth, smem, smem + 16384, block_m, nbase, 0, w, srow, schunk);
  __syncthreads();
  int cur = 0;

  for (int nt = 0; nt < 4; ++nt) {
    const int ncode = nbase + nt * BN;
    f32x4 acc[4][4];
#pragma unroll
    for (int ti = 0; ti < 4; ++ti)
#pragma unroll
      for (int tj = 0; tj < 4; ++tj) acc[ti][tj] = (f32x4){0.f, 0.f, 0.f, 0.f};

    for (int dtI = 0; dtI < 8; ++dtI) {
      // issue next tile's loads early (into the other buffer)
      char* nAh = smem + (cur ^ 1) * 32768;
      if (dtI < 7) {
        stage_tile(xh, Eth, nAh, nAh + 16384, block_m, ncode, (dtI + 1) * 64, w, srow,
                   schunk);
      } else if (nt < 3) {
        stage_tile(xh, Eth, nAh, nAh + 16384, block_m, ncode + BN, 0, w, srow, schunk);
      }

      // compute current buffer
      char* Ah = smem + cur * 32768;
      char* Bh = Ah + 16384;
#pragma unroll
      for (int s = 0; s < 2; ++s) {
        const int ch = ((s * 4 + quad) ^ rx) * 16;
        bf16x8 af[4], bfv[4];
#pragma unroll
        for (int t = 0; t < 4; ++t) {
          af[t] = *(const bf16x8*)(Ah + (wm * 64 + t * 16 + l15) * 128 + ch);
          bfv[t] = *(const bf16x8*)(Bh + (wk * 64 + t * 16 + l15) * 128 + ch);
        }
#pragma unroll
        for (int ti = 0; ti < 4; ++ti)
#pragma unroll
          for (int tj = 0; tj < 4; ++tj)
            acc[ti][tj] = __builtin_amdgcn_mfma_f32_16x16x32_bf16(af[ti], bfv[tj],
                                                                  acc[ti][tj], 0, 0, 0);
      }
      __syncthreads();  // drains next-tile vmcnt (post-compute) + cross-wave barrier
      cur ^= 1;
    }

    // fold this 128-code tile: score = dot - 0.5|e|^2
    const int colb = ncode + wk * 64 + l15;
#pragma unroll
    for (int tj = 0; tj < 4; ++tj) {
      float h = he2[colb + tj * 16];
#pragma unroll
      for (int ti = 0; ti < 4; ++ti)
#pragma unroll
        for (int r = 0; r < 4; ++r) {
          float sc = acc[ti][tj][r] - h;
          int slot = ti * 4 + r;
          if (sc > best[slot]) { best[slot] = sc; bidx[slot] = colb + tj * 16; }
        }
    }
  }

  // reduce over the 16 col-lanes per row group, then cross-block atomicMax
#pragma unroll
  for (int slot = 0; slot < 16; ++slot) {
    float v = best[slot];
    int ii = bidx[slot];
#pragma unroll
    for (int m = 1; m < 16; m <<= 1) {
      float ov = __shfl_xor(v, m, 64);
      int oi = __shfl_xor(ii, m, 64);
      if (ov > v || (ov == v && oi < ii)) { v = ov; ii = oi; }
    }
    if (l15 == 0) {
      int row = block_m + wm * 64 + (slot >> 2) * 16 + quad * 4 + (slot & 3);
      uint32_t b = __float_as_uint(v);
      uint32_t mm = (b & 0x80000000u) ? ~b : (b | 0x80000000u);
      unsigned long long packed = ((unsigned long long)mm << 32) | (uint32_t)(~(uint32_t)ii);
      atomicMax(&best64[row], packed);
    }
  }
}

// ---------------- fallback fp32 argmax (used when ws too small) ----------------
#define BM 128
#define BK 128
#define KS 4
#define KPB (KK / KS)
#define BD 32

__global__ __launch_bounds__(256, 4) void argmax_kernel(
    const float* __restrict__ x, const float* __restrict__ E,
    const float* __restrict__ he2, unsigned long long* __restrict__ best64) {
  __shared__ __align__(16) char smem[33280];
  float (*xs)[132] = (float (*)[132])smem;
  float (*es)[BK] = (float (*)[BK])(smem + 16896);

  const int tid = threadIdx.x;
  const int wave = tid >> 6;
  const int lane = tid & 63;
  const int wm = wave >> 1, wk = wave & 1;
  const int tm = lane >> 3, tk = lane & 7;
  const int block_m = (blockIdx.x >> 2) * BM;
  const int kbase = (blockIdx.x & 3) * KPB;

  float best[8];
  int bidx[8];
#pragma unroll
  for (int i = 0; i < 8; ++i) { best[i] = -INFINITY; bidx[i] = 0; }

  const int xtok = tid >> 3;
  const int xd4 = tid & 7;
  const int erow_lane = (lane >> 5);
  const int ecol = (lane & 31) * 4;

  for (int kt = 0; kt < KPB; kt += BK) {
    const int k0 = kbase + kt;
    float acc[8][8];
#pragma unroll
    for (int i = 0; i < 8; ++i)
#pragma unroll
      for (int j = 0; j < 8; ++j) acc[i][j] = 0.f;

    for (int dt = 0; dt < DD; dt += BD) {
      __syncthreads();
#pragma unroll
      for (int r = 0; r < 4; ++r) {
        int row = r * 8 + wave * 2;
        const float* gp = E + (size_t)(dt + row + erow_lane) * KK + k0 + ecol;
        __builtin_amdgcn_global_load_lds(
            (const __attribute__((address_space(1))) void*)gp,
            (__attribute__((address_space(3))) void*)&es[row][0], 16, 0, 0);
      }
#pragma unroll
      for (int r = 0; r < 4; ++r) {
        int tok = xtok + r * 32;
        float4 v = *(const float4*)(x + (size_t)(block_m + tok) * DD + dt + xd4 * 4);
        xs[xd4 * 4 + 0][tok] = v.x;
        xs[xd4 * 4 + 1][tok] = v.y;
        xs[xd4 * 4 + 2][tok] = v.z;
        xs[xd4 * 4 + 3][tok] = v.w;
      }
      __syncthreads();
#pragma unroll 4
      for (int d = 0; d < BD; ++d) {
        const float4 a0 = *(const float4*)&xs[d][wm * 64 + tm * 8];
        const float4 a1 = *(const float4*)&xs[d][wm * 64 + tm * 8 + 4];
        const float4 b0 = *(const float4*)&es[d][wk * 64 + tk * 8];
        const float4 b1 = *(const float4*)&es[d][wk * 64 + tk * 8 + 4];
        const float av[8] = {a0.x, a0.y, a0.z, a0.w, a1.x, a1.y, a1.z, a1.w};
        const float bv[8] = {b0.x, b0.y, b0.z, b0.w, b1.x, b1.y, b1.z, b1.w};
#pragma unroll
        for (int i = 0; i < 8; ++i)
#pragma unroll
          for (int j = 0; j < 8; ++j) acc[i][j] = fmaf(av[i], bv[j], acc[i][j]);
      }
    }
    const int kcol = k0 + wk * 64 + tk * 8;
    float4 h0 = *(const float4*)(he2 + kcol);
    float4 h1 = *(const float4*)(he2 + kcol + 4);
    const float hv[8] = {h0.x, h0.y, h0.z, h0.w, h1.x, h1.y, h1.z, h1.w};
#pragma unroll
    for (int i = 0; i < 8; ++i) {
#pragma unroll
      for (int j = 0; j < 8; ++j) {
        float s = acc[i][j] - hv[j];
        if (s > best[i]) { best[i] = s; bidx[i] = kcol + j; }
      }
    }
  }

  __syncthreads();
  float (*rv)[17] = (float (*)[17])smem;
  int (*ri)[17] = (int (*)[17])(smem + 8704);
#pragma unroll
  for (int i = 0; i < 8; ++i) {
    int tok = wm * 64 + tm * 8 + i;
    rv[tok][wk * 8 + tk] = best[i];
    ri[tok][wk * 8 + tk] = bidx[i];
  }
  __syncthreads();
  if (tid < BM) {
    float bv = rv[tid][0];
    int bi = ri[tid][0];
#pragma unroll
    for (int t = 1; t < 16; ++t) {
      float v = rv[tid][t];
      int ii = ri[tid][t];
      if (v > bv || (v == bv && ii < bi)) { bv = v; bi = ii; }
    }
    uint32_t b = __float_as_uint(bv);
    uint32_t m = (b & 0x80000000u) ? ~b : (b | 0x80000000u);
    unsigned long long packed = ((unsigned long long)m << 32) | (uint32_t)(~(uint32_t)bi);
    atomicMax(&best64[block_m + tid], packed);
  }
}

// ---- gather quantized + sum((q-x)^2) + counts, with fused last-block finalize ----
template <bool USE_ET>
__global__ __launch_bounds__(256) void gather_fin_kernel(
    const float* __restrict__ x, const float* __restrict__ Esrc,
    const unsigned long long* __restrict__ best64, float* __restrict__ out,
    float* __restrict__ partials, int* __restrict__ counts,
    unsigned int* __restrict__ done) {
  __shared__ float sh[256];
  __shared__ unsigned int ticket;
  int tid = threadIdx.x;
  int gid = blockIdx.x * 256 + tid;
  int n = gid >> 7;
  int d4 = gid & 127;
  int k = (int)(~(uint32_t)best64[n]);
  float4 q;
  if (USE_ET) {
    q = *(const float4*)(Esrc + (size_t)k * DD + d4 * 4);
  } else {
    q.x = Esrc[(size_t)(d4 * 4 + 0) * KK + k];
    q.y = Esrc[(size_t)(d4 * 4 + 1) * KK + k];
    q.z = Esrc[(size_t)(d4 * 4 + 2) * KK + k];
    q.w = Esrc[(size_t)(d4 * 4 + 3) * KK + k];
  }
  float4 xv = *(const float4*)(x + (size_t)n * DD + d4 * 4);
  *(float4*)(out + (size_t)n * DD + d4 * 4) = q;
  float dx0 = q.x - xv.x, dx1 = q.y - xv.y, dx2 = q.z - xv.z, dx3 = q.w - xv.w;
  sh[tid] = dx0 * dx0 + dx1 * dx1 + dx2 * dx2 + dx3 * dx3;
  if (d4 == 0) atomicAdd(&counts[k], 1);
  __syncthreads();
  for (int s = 128; s > 0; s >>= 1) {
    if (tid < s) sh[tid] += sh[tid + s];
    __syncthreads();
  }
  if (tid == 0) atomicAdd(&partials[blockIdx.x & 255], sh[0]);

  // last finished block runs finalize (counts/partials complete & fenced)
  __threadfence();
  __syncthreads();
  if (tid == 0) ticket = atomicAdd(done, 1u);
  __syncthreads();
  if (ticket != gridDim.x - 1) return;
  __threadfence();

  float h = 0.f;
  for (int k2 = tid; k2 < KK; k2 += 256) {
    float p = (float)counts[k2] * (1.0f / (float)NN);
    h += p * logf(p + 1e-10f);
  }
  sh[tid] = h;
  __syncthreads();
  for (int s = 128; s > 0; s >>= 1) {
    if (tid < s) sh[tid] += sh[tid + s];
    __syncthreads();
  }
  float H = sh[0];
  __syncthreads();
  sh[tid] = partials[tid];
  __syncthreads();
  for (int s = 128; s > 0; s >>= 1) {
    if (tid < s) sh[tid] += sh[tid + s];
    __syncthreads();
  }
  if (tid == 0) {
    float mse = sh[0] / (float)((size_t)NN * DD);
    out[(size_t)NN * DD] = 1.25f * mse;
    out[(size_t)NN * DD + 1] = expf(-H);
  }
}

extern "C" void kernel_launch(void* const* d_in, const int* in_sizes, int n_in,
                              void* d_out, int out_size, void* d_ws, size_t ws_size,
                              hipStream_t stream) {
  const float* x = (const float*)d_in[0];
  const float* E = (const float*)d_in[1];
  float* out = (float*)d_out;
  char* ws = (char*)d_ws;

  // ws layout
  unsigned long long* best64 = (unsigned long long*)(ws + 0);  // 262144
  float* he2 = (float*)(ws + 262144);                          // 16384
  int* counts = (int*)(ws + 278528);                           // 16384
  float* partials = (float*)(ws + 294912);                     // 1024
  unsigned int* done = (unsigned int*)(ws + 295936);           // 4 (+pad to 296192)
  unsigned short* Eth = (unsigned short*)(ws + 296192);        // 4 MiB
  float* Et = (float*)(ws + 4490496);                          // 8 MiB (optional)
  const size_t NEED_MFMA = 4490496;
  const size_t NEED_ET = 4490496 + (size_t)DD * KK * 4;

  // zero best64 + he2 + counts + partials + done
  hipMemsetAsync(ws, 0, 296192, stream);

  if (ws_size >= NEED_MFMA) {
    unsigned short* xh = (unsigned short*)d_out;  // overwritten by gather later
    const bool use_et = ws_size >= NEED_ET;

    if (use_et)
      prep_fused_kernel<true><<<2048 + 8192, 256, 0, stream>>>((const float4*)x, xh, E,
                                                               Eth, he2, Et);
    else
      prep_fused_kernel<false><<<2048 + 8192, 256, 0, stream>>>((const float4*)x, xh, E,
                                                                Eth, he2, Et);
    argmax_mfma_kernel<<<(NN / 128) * 8, 256, 0, stream>>>(xh, Eth, he2, best64);
    if (use_et)
      gather_fin_kernel<true><<<(NN * (DD / 4)) / 256, 256, 0, stream>>>(
          x, Et, best64, out, partials, counts, done);
    else
      gather_fin_kernel<false><<<(NN * (DD / 4)) / 256, 256, 0, stream>>>(
          x, E, best64, out, partials, counts, done);
  } else {
    // fp32 fallback: prep for he2 only (Eth region scratch), then fp32 argmax
    prep_fused_kernel<false><<<2048 + 8192, 256, 0, stream>>>(
        (const float4*)x, (unsigned short*)d_out, E, Eth, he2, (float*)nullptr);
    argmax_kernel<<<(NN / BM) * KS, 256, 0, stream>>>(x, E, he2, best64);
    gather_fin_kernel<false><<<(NN * (DD / 4)) / 256, 256, 0, stream>>>(
        x, E, best64, out, partials, counts, done);
  }
}

// Round 8
// 324.180 us; speedup vs baseline: 5.3835x; 5.3835x over previous
//
#include <hip/hip_runtime.h>
#include <stdint.h>

#define DD 512
#define KK 4096
#define NN 32768

typedef __attribute__((ext_vector_type(8))) short bf16x8;
typedef __attribute__((ext_vector_type(4))) float f32x4;

__device__ __forceinline__ unsigned short bf16_rn(float f) {
  uint32_t u = __float_as_uint(f);
  return (unsigned short)((u + 0x7FFFu + ((u >> 16) & 1u)) >> 16);
}

// ---- fused prep: blocks [0,2048) do E transpose/bf16/he2; [2048,10240) do x->bf16 ----
// (independent work, one launch; NO cross-block communication -> safe fusion.
//  DO NOT fuse finalize into gather via threadfence/ticket: device-scope fence
//  = per-block L2 writeback on 8 non-coherent XCD L2s -> 35us became 1449us, R7.)
template <bool WRITE_ET>
__global__ __launch_bounds__(256) void prep_fused_kernel(
    const float4* __restrict__ x4, unsigned short* __restrict__ xh,
    const float* __restrict__ E, unsigned short* __restrict__ Eth,
    float* __restrict__ he2, float* __restrict__ Et) {
  __shared__ float t[32][33];
  const int bid = blockIdx.x;
  if (bid < 2048) {
    // E prep: transpose + bf16 + he2 (wave-shfl reduce, one atomic per (k,wave))
    int bk = (bid & 127) * 32;
    int bd = (bid >> 7) * 32;
    int c = threadIdx.x & 31;
    int r0 = threadIdx.x >> 5;
#pragma unroll
    for (int r = r0; r < 32; r += 8) t[r][c] = E[(size_t)(bd + r) * KK + bk + c];
    __syncthreads();
#pragma unroll
    for (int i = 0; i < 4; ++i) {
      int r = r0 + i * 8;
      float v = t[c][r];  // = E[(bd+c)*KK + bk+r]  (k = bk+r, d = bd+c)
      size_t o = (size_t)(bk + r) * DD + bd + c;
      Eth[o] = bf16_rn(v);
      if (WRITE_ET) Et[o] = v;
      float v2 = v * v;
#pragma unroll
      for (int m = 1; m < 32; m <<= 1) v2 += __shfl_xor(v2, m, 64);
      if (c == 0) atomicAdd(&he2[bk + r], 0.5f * v2);
    }
  } else {
    // x -> bf16 cast (8 elems/thread)
    int gid = (bid - 2048) * 256 + threadIdx.x;
    float4 a = x4[gid * 2];
    float4 b = x4[gid * 2 + 1];
    union { unsigned short u[8]; uint4 q; } H;
    H.u[0] = bf16_rn(a.x); H.u[1] = bf16_rn(a.y);
    H.u[2] = bf16_rn(a.z); H.u[3] = bf16_rn(a.w);
    H.u[4] = bf16_rn(b.x); H.u[5] = bf16_rn(b.y);
    H.u[6] = bf16_rn(b.z); H.u[7] = bf16_rn(b.w);
    *(uint4*)(xh + (size_t)gid * 8) = H.q;
  }
}

// ---------------- MFMA scores + argmax (R3 kernel, verbatim) ----------------
// grid: (NN/128)*8 remapped XCD-aware; block = 128 tokens x 512 codes (4 nt tiles).
// LDS: double-buffered A,B tiles [128][64] bf16 (rows = 128 B), XOR-swizzled chunks:
//   LDS slot (row, pos) holds global 16B-chunk (pos ^ (row&7)).
// Schedule: issue next tile's global_load_lds BEFORE computing the current tile;
// single __syncthreads per step. Measured: 178us, MfmaUtil 33.7, FETCH 92MB, 128 VGPR.
// DO NOT: launch_bounds(256,4) [VGPR->64, spill, R6]; nt-unroll+hv preload [scratch,
// R4]; counted-vmcnt 2-barrier graft [190us, R5].
#define ANB 512
#define BN 128

__device__ __forceinline__ void stage_tile(const unsigned short* __restrict__ xh,
                                           const unsigned short* __restrict__ Eth,
                                           char* Ah, char* Bh, int block_m, int ncode,
                                           int dt, int w, int srow, int schunk) {
#pragma unroll
  for (int r = 0; r < 4; ++r) {
    const int rowbase = w * 32 + r * 8;
    const int arow = block_m + rowbase + srow;
    const int brow = ncode + rowbase + srow;
    const int col = dt + schunk * 8;
    __builtin_amdgcn_global_load_lds(
        (const __attribute__((address_space(1))) void*)(xh + (size_t)arow * DD + col),
        (__attribute__((address_space(3))) void*)(Ah + rowbase * 128), 16, 0, 0);
    __builtin_amdgcn_global_load_lds(
        (const __attribute__((address_space(1))) void*)(Eth + (size_t)brow * DD + col),
        (__attribute__((address_space(3))) void*)(Bh + rowbase * 128), 16, 0, 0);
  }
}

__global__ __launch_bounds__(256, 2) void argmax_mfma_kernel(
    const unsigned short* __restrict__ xh, const unsigned short* __restrict__ Eth,
    const float* __restrict__ he2, unsigned long long* __restrict__ best64) {
  __shared__ __align__(16) char smem[65536];  // 2 x {A[128][64], B[128][64]} bf16

  const int tid = threadIdx.x;
  const int w = tid >> 6;
  const int lane = tid & 63;
  const int wm = w >> 1, wk = w & 1;
  const int l15 = lane & 15, quad = lane >> 4;

  // XCD-aware bijective swizzle: 2048 wgs, 8 XCDs (wg -> XCD = blockIdx%8).
  const int orig = blockIdx.x;
  const int wgid = (orig & 7) * 256 + (orig >> 3);
  const int block_m = (wgid >> 3) * BN;
  const int nbase = (wgid & 7) * ANB;

  const int srow = lane >> 3;                       // 0..7 row within 8-row group
  const int schunk = (lane & 7) ^ (lane >> 3);      // swizzled source chunk
  const int rx = l15 & 7;                           // frag-read xor key

  float best[16];
  int bidx[16];
#pragma unroll
  for (int s = 0; s < 16; ++s) { best[s] = -INFINITY; bidx[s] = 0; }

  // prologue: stage (nt=0, dt=0) into buf 0
  stage_tile(xh, Eth, smem, smem + 16384, block_m, nbase, 0, w, srow, schunk);
  __syncthreads();
  int cur = 0;

  for (int nt = 0; nt < 4; ++nt) {
    const int ncode = nbase + nt * BN;
    f32x4 acc[4][4];
#pragma unroll
    for (int ti = 0; ti < 4; ++ti)
#pragma unroll
      for (int tj = 0; tj < 4; ++tj) acc[ti][tj] = (f32x4){0.f, 0.f, 0.f, 0.f};

    for (int dtI = 0; dtI < 8; ++dtI) {
      // issue next tile's loads early (into the other buffer)
      char* nAh = smem + (cur ^ 1) * 32768;
      if (dtI < 7) {
        stage_tile(xh, Eth, nAh, nAh + 16384, block_m, ncode, (dtI + 1) * 64, w, srow,
                   schunk);
      } else if (nt < 3) {
        stage_tile(xh, Eth, nAh, nAh + 16384, block_m, ncode + BN, 0, w, srow, schunk);
      }

      // compute current buffer
      char* Ah = smem + cur * 32768;
      char* Bh = Ah + 16384;
#pragma unroll
      for (int s = 0; s < 2; ++s) {
        const int ch = ((s * 4 + quad) ^ rx) * 16;
        bf16x8 af[4], bfv[4];
#pragma unroll
        for (int t = 0; t < 4; ++t) {
          af[t] = *(const bf16x8*)(Ah + (wm * 64 + t * 16 + l15) * 128 + ch);
          bfv[t] = *(const bf16x8*)(Bh + (wk * 64 + t * 16 + l15) * 128 + ch);
        }
#pragma unroll
        for (int ti = 0; ti < 4; ++ti)
#pragma unroll
          for (int tj = 0; tj < 4; ++tj)
            acc[ti][tj] = __builtin_amdgcn_mfma_f32_16x16x32_bf16(af[ti], bfv[tj],
                                                                  acc[ti][tj], 0, 0, 0);
      }
      __syncthreads();  // drains next-tile vmcnt (post-compute) + cross-wave barrier
      cur ^= 1;
    }

    // fold this 128-code tile: score = dot - 0.5|e|^2
    const int colb = ncode + wk * 64 + l15;
#pragma unroll
    for (int tj = 0; tj < 4; ++tj) {
      float h = he2[colb + tj * 16];
#pragma unroll
      for (int ti = 0; ti < 4; ++ti)
#pragma unroll
        for (int r = 0; r < 4; ++r) {
          float sc = acc[ti][tj][r] - h;
          int slot = ti * 4 + r;
          if (sc > best[slot]) { best[slot] = sc; bidx[slot] = colb + tj * 16; }
        }
    }
  }

  // reduce over the 16 col-lanes per row group, then cross-block atomicMax
#pragma unroll
  for (int slot = 0; slot < 16; ++slot) {
    float v = best[slot];
    int ii = bidx[slot];
#pragma unroll
    for (int m = 1; m < 16; m <<= 1) {
      float ov = __shfl_xor(v, m, 64);
      int oi = __shfl_xor(ii, m, 64);
      if (ov > v || (ov == v && oi < ii)) { v = ov; ii = oi; }
    }
    if (l15 == 0) {
      int row = block_m + wm * 64 + (slot >> 2) * 16 + quad * 4 + (slot & 3);
      uint32_t b = __float_as_uint(v);
      uint32_t mm = (b & 0x80000000u) ? ~b : (b | 0x80000000u);
      unsigned long long packed = ((unsigned long long)mm << 32) | (uint32_t)(~(uint32_t)ii);
      atomicMax(&best64[row], packed);
    }
  }
}

// ---------------- fallback fp32 argmax (used when ws too small) ----------------
#define BM 128
#define BK 128
#define KS 4
#define KPB (KK / KS)
#define BD 32

__global__ __launch_bounds__(256, 4) void argmax_kernel(
    const float* __restrict__ x, const float* __restrict__ E,
    const float* __restrict__ he2, unsigned long long* __restrict__ best64) {
  __shared__ __align__(16) char smem[33280];
  float (*xs)[132] = (float (*)[132])smem;
  float (*es)[BK] = (float (*)[BK])(smem + 16896);

  const int tid = threadIdx.x;
  const int wave = tid >> 6;
  const int lane = tid & 63;
  const int wm = wave >> 1, wk = wave & 1;
  const int tm = lane >> 3, tk = lane & 7;
  const int block_m = (blockIdx.x >> 2) * BM;
  const int kbase = (blockIdx.x & 3) * KPB;

  float best[8];
  int bidx[8];
#pragma unroll
  for (int i = 0; i < 8; ++i) { best[i] = -INFINITY; bidx[i] = 0; }

  const int xtok = tid >> 3;
  const int xd4 = tid & 7;
  const int erow_lane = (lane >> 5);
  const int ecol = (lane & 31) * 4;

  for (int kt = 0; kt < KPB; kt += BK) {
    const int k0 = kbase + kt;
    float acc[8][8];
#pragma unroll
    for (int i = 0; i < 8; ++i)
#pragma unroll
      for (int j = 0; j < 8; ++j) acc[i][j] = 0.f;

    for (int dt = 0; dt < DD; dt += BD) {
      __syncthreads();
#pragma unroll
      for (int r = 0; r < 4; ++r) {
        int row = r * 8 + wave * 2;
        const float* gp = E + (size_t)(dt + row + erow_lane) * KK + k0 + ecol;
        __builtin_amdgcn_global_load_lds(
            (const __attribute__((address_space(1))) void*)gp,
            (__attribute__((address_space(3))) void*)&es[row][0], 16, 0, 0);
      }
#pragma unroll
      for (int r = 0; r < 4; ++r) {
        int tok = xtok + r * 32;
        float4 v = *(const float4*)(x + (size_t)(block_m + tok) * DD + dt + xd4 * 4);
        xs[xd4 * 4 + 0][tok] = v.x;
        xs[xd4 * 4 + 1][tok] = v.y;
        xs[xd4 * 4 + 2][tok] = v.z;
        xs[xd4 * 4 + 3][tok] = v.w;
      }
      __syncthreads();
#pragma unroll 4
      for (int d = 0; d < BD; ++d) {
        const float4 a0 = *(const float4*)&xs[d][wm * 64 + tm * 8];
        const float4 a1 = *(const float4*)&xs[d][wm * 64 + tm * 8 + 4];
        const float4 b0 = *(const float4*)&es[d][wk * 64 + tk * 8];
        const float4 b1 = *(const float4*)&es[d][wk * 64 + tk * 8 + 4];
        const float av[8] = {a0.x, a0.y, a0.z, a0.w, a1.x, a1.y, a1.z, a1.w};
        const float bv[8] = {b0.x, b0.y, b0.z, b0.w, b1.x, b1.y, b1.z, b1.w};
#pragma unroll
        for (int i = 0; i < 8; ++i)
#pragma unroll
          for (int j = 0; j < 8; ++j) acc[i][j] = fmaf(av[i], bv[j], acc[i][j]);
      }
    }
    const int kcol = k0 + wk * 64 + tk * 8;
    float4 h0 = *(const float4*)(he2 + kcol);
    float4 h1 = *(const float4*)(he2 + kcol + 4);
    const float hv[8] = {h0.x, h0.y, h0.z, h0.w, h1.x, h1.y, h1.z, h1.w};
#pragma unroll
    for (int i = 0; i < 8; ++i) {
#pragma unroll
      for (int j = 0; j < 8; ++j) {
        float s = acc[i][j] - hv[j];
        if (s > best[i]) { best[i] = s; bidx[i] = kcol + j; }
      }
    }
  }

  __syncthreads();
  float (*rv)[17] = (float (*)[17])smem;
  int (*ri)[17] = (int (*)[17])(smem + 8704);
#pragma unroll
  for (int i = 0; i < 8; ++i) {
    int tok = wm * 64 + tm * 8 + i;
    rv[tok][wk * 8 + tk] = best[i];
    ri[tok][wk * 8 + tk] = bidx[i];
  }
  __syncthreads();
  if (tid < BM) {
    float bv = rv[tid][0];
    int bi = ri[tid][0];
#pragma unroll
    for (int t = 1; t < 16; ++t) {
      float v = rv[tid][t];
      int ii = ri[tid][t];
      if (v > bv || (v == bv && ii < bi)) { bv = v; bi = ii; }
    }
    uint32_t b = __float_as_uint(bv);
    uint32_t m = (b & 0x80000000u) ? ~b : (b | 0x80000000u);
    unsigned long long packed = ((unsigned long long)m << 32) | (uint32_t)(~(uint32_t)bi);
    atomicMax(&best64[block_m + tid], packed);
  }
}

// ---------------- gather quantized + sum((q-x)^2) + counts ----------------
__global__ __launch_bounds__(256) void gather_et_kernel(
    const float* __restrict__ x, const float* __restrict__ Et,
    const unsigned long long* __restrict__ best64, float* __restrict__ out,
    float* __restrict__ partials, int* __restrict__ counts) {
  __shared__ float sh[256];
  int tid = threadIdx.x;
  int gid = blockIdx.x * 256 + tid;
  int n = gid >> 7;
  int d4 = gid & 127;
  int k = (int)(~(uint32_t)best64[n]);
  float4 q = *(const float4*)(Et + (size_t)k * DD + d4 * 4);
  float4 xv = *(const float4*)(x + (size_t)n * DD + d4 * 4);
  *(float4*)(out + (size_t)n * DD + d4 * 4) = q;
  float dx0 = q.x - xv.x, dx1 = q.y - xv.y, dx2 = q.z - xv.z, dx3 = q.w - xv.w;
  sh[tid] = dx0 * dx0 + dx1 * dx1 + dx2 * dx2 + dx3 * dx3;
  if (d4 == 0) atomicAdd(&counts[k], 1);
  __syncthreads();
  for (int s = 128; s > 0; s >>= 1) {
    if (tid < s) sh[tid] += sh[tid + s];
    __syncthreads();
  }
  if (tid == 0) atomicAdd(&partials[blockIdx.x & 255], sh[0]);
}

__global__ __launch_bounds__(256) void gather_direct_kernel(
    const float* __restrict__ x, const float* __restrict__ E,
    const unsigned long long* __restrict__ best64, float* __restrict__ out,
    float* __restrict__ partials, int* __restrict__ counts) {
  __shared__ float sh[256];
  int tid = threadIdx.x;
  int gid = blockIdx.x * 256 + tid;
  int n = gid >> 7;
  int d4 = gid & 127;
  int k = (int)(~(uint32_t)best64[n]);
  float4 q;
  q.x = E[(size_t)(d4 * 4 + 0) * KK + k];
  q.y = E[(size_t)(d4 * 4 + 1) * KK + k];
  q.z = E[(size_t)(d4 * 4 + 2) * KK + k];
  q.w = E[(size_t)(d4 * 4 + 3) * KK + k];
  float4 xv = *(const float4*)(x + (size_t)n * DD + d4 * 4);
  *(float4*)(out + (size_t)n * DD + d4 * 4) = q;
  float dx0 = q.x - xv.x, dx1 = q.y - xv.y, dx2 = q.z - xv.z, dx3 = q.w - xv.w;
  sh[tid] = dx0 * dx0 + dx1 * dx1 + dx2 * dx2 + dx3 * dx3;
  if (d4 == 0) atomicAdd(&counts[k], 1);
  __syncthreads();
  for (int s = 128; s > 0; s >>= 1) {
    if (tid < s) sh[tid] += sh[tid + s];
    __syncthreads();
  }
  if (tid == 0) atomicAdd(&partials[blockIdx.x & 255], sh[0]);
}

// ---------------- loss + perplexity ----------------
__global__ __launch_bounds__(256) void finalize_kernel(
    const int* __restrict__ counts, const float* __restrict__ partials,
    float* __restrict__ out) {
  __shared__ float sh[256];
  int tid = threadIdx.x;
  float h = 0.f;
  for (int k = tid; k < KK; k += 256) {
    float p = (float)counts[k] * (1.0f / (float)NN);
    h += p * logf(p + 1e-10f);
  }
  sh[tid] = h;
  __syncthreads();
  for (int s = 128; s > 0; s >>= 1) {
    if (tid < s) sh[tid] += sh[tid + s];
    __syncthreads();
  }
  float H = sh[0];
  __syncthreads();
  sh[tid] = partials[tid];
  __syncthreads();
  for (int s = 128; s > 0; s >>= 1) {
    if (tid < s) sh[tid] += sh[tid + s];
    __syncthreads();
  }
  if (tid == 0) {
    float mse = sh[0] / (float)((size_t)NN * DD);
    out[(size_t)NN * DD] = 1.25f * mse;
    out[(size_t)NN * DD + 1] = expf(-H);
  }
}

extern "C" void kernel_launch(void* const* d_in, const int* in_sizes, int n_in,
                              void* d_out, int out_size, void* d_ws, size_t ws_size,
                              hipStream_t stream) {
  const float* x = (const float*)d_in[0];
  const float* E = (const float*)d_in[1];
  float* out = (float*)d_out;
  char* ws = (char*)d_ws;

  // ws layout
  unsigned long long* best64 = (unsigned long long*)(ws + 0);  // 262144
  float* he2 = (float*)(ws + 262144);                          // 16384
  int* counts = (int*)(ws + 278528);                           // 16384
  float* partials = (float*)(ws + 294912);                     // 1024
  unsigned short* Eth = (unsigned short*)(ws + 295936);        // 4 MiB
  float* Et = (float*)(ws + 4490240);                          // 8 MiB (optional)
  const size_t NEED_MFMA = 4490240;
  const size_t NEED_ET = 4490240 + (size_t)DD * KK * 4;

  // zero best64 + he2 + counts + partials
  hipMemsetAsync(ws, 0, 295936, stream);

  if (ws_size >= NEED_MFMA) {
    unsigned short* xh = (unsigned short*)d_out;  // overwritten by gather later
    const bool use_et = ws_size >= NEED_ET;

    if (use_et)
      prep_fused_kernel<true><<<2048 + 8192, 256, 0, stream>>>((const float4*)x, xh, E,
                                                               Eth, he2, Et);
    else
      prep_fused_kernel<false><<<2048 + 8192, 256, 0, stream>>>((const float4*)x, xh, E,
                                                                Eth, he2, Et);
    argmax_mfma_kernel<<<(NN / 128) * 8, 256, 0, stream>>>(xh, Eth, he2, best64);
    if (use_et)
      gather_et_kernel<<<(NN * (DD / 4)) / 256, 256, 0, stream>>>(x, Et, best64, out,
                                                                  partials, counts);
    else
      gather_direct_kernel<<<(NN * (DD / 4)) / 256, 256, 0, stream>>>(x, E, best64, out,
                                                                      partials, counts);
  } else {
    // fp32 fallback: prep for he2 only (Eth region scratch), then fp32 argmax
    prep_fused_kernel<false><<<2048 + 8192, 256, 0, stream>>>(
        (const float4*)x, (unsigned short*)d_out, E, Eth, he2, (float*)nullptr);
    argmax_kernel<<<(NN / BM) * KS, 256, 0, stream>>>(x, E, he2, best64);
    gather_direct_kernel<<<(NN * (DD / 4)) / 256, 256, 0, stream>>>(x, E, best64, out,
                                                                    partials, counts);
  }
  finalize_kernel<<<1, 256, 0, stream>>>(counts, partials, out);
}

// Round 9
// 319.820 us; speedup vs baseline: 5.4569x; 1.0136x over previous
//
#include <hip/hip_runtime.h>
#include <stdint.h>

#define DD 512
#define KK 4096
#define NN 32768

typedef __attribute__((ext_vector_type(8))) short bf16x8;
typedef __attribute__((ext_vector_type(4))) float f32x4;

__device__ __forceinline__ unsigned short bf16_rn(float f) {
  uint32_t u = __float_as_uint(f);
  return (unsigned short)((u + 0x7FFFu + ((u >> 16) & 1u)) >> 16);
}

// ---- fused prep: blocks [0,2048) do E transpose/bf16/he2; [2048,10240) do x->bf16 ----
// (independent work, one launch; NO cross-block communication -> safe fusion.
//  DO NOT fuse finalize into gather via threadfence/ticket: device-scope fence
//  = per-block L2 writeback on 8 non-coherent XCD L2s -> 35us became 1449us, R7.)
template <bool WRITE_ET>
__global__ __launch_bounds__(256) void prep_fused_kernel(
    const float4* __restrict__ x4, unsigned short* __restrict__ xh,
    const float* __restrict__ E, unsigned short* __restrict__ Eth,
    float* __restrict__ he2, float* __restrict__ Et) {
  __shared__ float t[32][33];
  const int bid = blockIdx.x;
  if (bid < 2048) {
    // E prep: transpose + bf16 + he2 (wave-shfl reduce, one atomic per (k,wave))
    int bk = (bid & 127) * 32;
    int bd = (bid >> 7) * 32;
    int c = threadIdx.x & 31;
    int r0 = threadIdx.x >> 5;
#pragma unroll
    for (int r = r0; r < 32; r += 8) t[r][c] = E[(size_t)(bd + r) * KK + bk + c];
    __syncthreads();
#pragma unroll
    for (int i = 0; i < 4; ++i) {
      int r = r0 + i * 8;
      float v = t[c][r];  // = E[(bd+c)*KK + bk+r]  (k = bk+r, d = bd+c)
      size_t o = (size_t)(bk + r) * DD + bd + c;
      Eth[o] = bf16_rn(v);
      if (WRITE_ET) Et[o] = v;
      float v2 = v * v;
#pragma unroll
      for (int m = 1; m < 32; m <<= 1) v2 += __shfl_xor(v2, m, 64);
      if (c == 0) atomicAdd(&he2[bk + r], 0.5f * v2);
    }
  } else {
    // x -> bf16 cast (8 elems/thread)
    int gid = (bid - 2048) * 256 + threadIdx.x;
    float4 a = x4[gid * 2];
    float4 b = x4[gid * 2 + 1];
    union { unsigned short u[8]; uint4 q; } H;
    H.u[0] = bf16_rn(a.x); H.u[1] = bf16_rn(a.y);
    H.u[2] = bf16_rn(a.z); H.u[3] = bf16_rn(a.w);
    H.u[4] = bf16_rn(b.x); H.u[5] = bf16_rn(b.y);
    H.u[6] = bf16_rn(b.z); H.u[7] = bf16_rn(b.w);
    *(uint4*)(xh + (size_t)gid * 8) = H.q;
  }
}

// ---------------- MFMA scores + argmax (single bf16 product) ----------------
// R9: BM 128->256 (m93 "bigger tile" step). 512 threads = 8 waves (4x2 wave grid,
// wm in 0..3 / wk in 0..1); per-wave fragment code identical to the proven R3 kernel.
// grid: (NN/256)*8 = 1024, XCD-aware bijective swizzle.
// LDS: dbuf 2 x {A[256][64] 32KB + B[128][64] 16KB} = 96 KB, row stride 128 B,
// XOR-swizzled 16B chunks: slot (row,pos) holds global chunk (pos ^ (row&7)).
// Schedule (R3-proven, DO NOT TOUCH): stage(t+1) into other buf BEFORE compute(t),
// one __syncthreads per step (drains vmcnt + WAR). Amortization vs R3: staging
// 64->48 KB per 256x128 output per step, barrier events per MFMA halved.
// DO NOT: launch_bounds min-waves > 2 [VGPR clamp -> spill, R6]; nt-unroll + hv
// preload [dyn-index scratch, R4]; counted-vmcnt 2-barrier graft [190us, R5].
#define ANB 512
#define BN 128
#define BMT 256

__device__ __forceinline__ void stage_tile2(const unsigned short* __restrict__ xh,
                                            const unsigned short* __restrict__ Eth,
                                            char* Ah, char* Bh, int block_m, int ncode,
                                            int dt, int w, int srow, int schunk) {
  const int col = dt + schunk * 8;
  // A: 256 rows = 8 waves x 4 iters x 8 rows
#pragma unroll
  for (int r = 0; r < 4; ++r) {
    const int rowbase = w * 32 + r * 8;
    const int arow = block_m + rowbase + srow;
    __builtin_amdgcn_global_load_lds(
        (const __attribute__((address_space(1))) void*)(xh + (size_t)arow * DD + col),
        (__attribute__((address_space(3))) void*)(Ah + rowbase * 128), 16, 0, 0);
  }
  // B: 128 rows = 8 waves x 2 iters x 8 rows
#pragma unroll
  for (int r = 0; r < 2; ++r) {
    const int rowbase = w * 16 + r * 8;
    const int brow = ncode + rowbase + srow;
    __builtin_amdgcn_global_load_lds(
        (const __attribute__((address_space(1))) void*)(Eth + (size_t)brow * DD + col),
        (__attribute__((address_space(3))) void*)(Bh + rowbase * 128), 16, 0, 0);
  }
}

__global__ __launch_bounds__(512, 2) void argmax_mfma_kernel(
    const unsigned short* __restrict__ xh, const unsigned short* __restrict__ Eth,
    const float* __restrict__ he2, unsigned long long* __restrict__ best64) {
  __shared__ __align__(16) char smem[98304];  // 2 x {A[256][64] + B[128][64]} bf16

  const int tid = threadIdx.x;
  const int w = tid >> 6;                     // 0..7
  const int lane = tid & 63;
  const int wm = w >> 1, wk = w & 1;          // 4x2 wave grid
  const int l15 = lane & 15, quad = lane >> 4;

  // XCD-aware bijective swizzle: 1024 wgs, 8 XCDs (wg -> XCD = blockIdx%8).
  // XCD x owns wgid in [x*128,(x+1)*128): 16 token groups, 8 nbase-siblings each
  // consecutive -> shared A rows stay in that XCD's L2.
  const int orig = blockIdx.x;
  const int wgid = (orig & 7) * 128 + (orig >> 3);
  const int block_m = (wgid >> 3) * BMT;
  const int nbase = (wgid & 7) * ANB;

  const int srow = lane >> 3;                       // 0..7 row within 8-row group
  const int schunk = (lane & 7) ^ (lane >> 3);      // swizzled source chunk
  const int rx = l15 & 7;                           // frag-read xor key

  float best[16];
  int bidx[16];
#pragma unroll
  for (int s = 0; s < 16; ++s) { best[s] = -INFINITY; bidx[s] = 0; }

  // prologue: stage (nt=0, dt=0) into buf 0
  stage_tile2(xh, Eth, smem, smem + 32768, block_m, nbase, 0, w, srow, schunk);
  __syncthreads();
  int cur = 0;

  for (int nt = 0; nt < 4; ++nt) {
    const int ncode = nbase + nt * BN;
    f32x4 acc[4][4];
#pragma unroll
    for (int ti = 0; ti < 4; ++ti)
#pragma unroll
      for (int tj = 0; tj < 4; ++tj) acc[ti][tj] = (f32x4){0.f, 0.f, 0.f, 0.f};

    for (int dtI = 0; dtI < 8; ++dtI) {
      // issue next tile's loads early (into the other buffer)
      char* nAh = smem + (cur ^ 1) * 49152;
      if (dtI < 7) {
        stage_tile2(xh, Eth, nAh, nAh + 32768, block_m, ncode, (dtI + 1) * 64, w, srow,
                    schunk);
      } else if (nt < 3) {
        stage_tile2(xh, Eth, nAh, nAh + 32768, block_m, ncode + BN, 0, w, srow, schunk);
      }

      // compute current buffer
      char* Ah = smem + cur * 49152;
      char* Bh = Ah + 32768;
#pragma unroll
      for (int s = 0; s < 2; ++s) {
        const int ch = ((s * 4 + quad) ^ rx) * 16;
        bf16x8 af[4], bfv[4];
#pragma unroll
        for (int t = 0; t < 4; ++t) {
          af[t] = *(const bf16x8*)(Ah + (wm * 64 + t * 16 + l15) * 128 + ch);
          bfv[t] = *(const bf16x8*)(Bh + (wk * 64 + t * 16 + l15) * 128 + ch);
        }
#pragma unroll
        for (int ti = 0; ti < 4; ++ti)
#pragma unroll
          for (int tj = 0; tj < 4; ++tj)
            acc[ti][tj] = __builtin_amdgcn_mfma_f32_16x16x32_bf16(af[ti], bfv[tj],
                                                                  acc[ti][tj], 0, 0, 0);
      }
      __syncthreads();  // drains next-tile vmcnt (post-compute) + cross-wave barrier
      cur ^= 1;
    }

    // fold this 128-code tile: score = dot - 0.5|e|^2
    const int colb = ncode + wk * 64 + l15;
#pragma unroll
    for (int tj = 0; tj < 4; ++tj) {
      float h = he2[colb + tj * 16];
#pragma unroll
      for (int ti = 0; ti < 4; ++ti)
#pragma unroll
        for (int r = 0; r < 4; ++r) {
          float sc = acc[ti][tj][r] - h;
          int slot = ti * 4 + r;
          if (sc > best[slot]) { best[slot] = sc; bidx[slot] = colb + tj * 16; }
        }
    }
  }

  // reduce over the 16 col-lanes per row group, then cross-block atomicMax
#pragma unroll
  for (int slot = 0; slot < 16; ++slot) {
    float v = best[slot];
    int ii = bidx[slot];
#pragma unroll
    for (int m = 1; m < 16; m <<= 1) {
      float ov = __shfl_xor(v, m, 64);
      int oi = __shfl_xor(ii, m, 64);
      if (ov > v || (ov == v && oi < ii)) { v = ov; ii = oi; }
    }
    if (l15 == 0) {
      int row = block_m + wm * 64 + (slot >> 2) * 16 + quad * 4 + (slot & 3);
      uint32_t b = __float_as_uint(v);
      uint32_t mm = (b & 0x80000000u) ? ~b : (b | 0x80000000u);
      unsigned long long packed = ((unsigned long long)mm << 32) | (uint32_t)(~(uint32_t)ii);
      atomicMax(&best64[row], packed);
    }
  }
}

// ---------------- fallback fp32 argmax (used when ws too small) ----------------
#define BM 128
#define BK 128
#define KS 4
#define KPB (KK / KS)
#define BD 32

__global__ __launch_bounds__(256, 4) void argmax_kernel(
    const float* __restrict__ x, const float* __restrict__ E,
    const float* __restrict__ he2, unsigned long long* __restrict__ best64) {
  __shared__ __align__(16) char smem[33280];
  float (*xs)[132] = (float (*)[132])smem;
  float (*es)[BK] = (float (*)[BK])(smem + 16896);

  const int tid = threadIdx.x;
  const int wave = tid >> 6;
  const int lane = tid & 63;
  const int wm = wave >> 1, wk = wave & 1;
  const int tm = lane >> 3, tk = lane & 7;
  const int block_m = (blockIdx.x >> 2) * BM;
  const int kbase = (blockIdx.x & 3) * KPB;

  float best[8];
  int bidx[8];
#pragma unroll
  for (int i = 0; i < 8; ++i) { best[i] = -INFINITY; bidx[i] = 0; }

  const int xtok = tid >> 3;
  const int xd4 = tid & 7;
  const int erow_lane = (lane >> 5);
  const int ecol = (lane & 31) * 4;

  for (int kt = 0; kt < KPB; kt += BK) {
    const int k0 = kbase + kt;
    float acc[8][8];
#pragma unroll
    for (int i = 0; i < 8; ++i)
#pragma unroll
      for (int j = 0; j < 8; ++j) acc[i][j] = 0.f;

    for (int dt = 0; dt < DD; dt += BD) {
      __syncthreads();
#pragma unroll
      for (int r = 0; r < 4; ++r) {
        int row = r * 8 + wave * 2;
        const float* gp = E + (size_t)(dt + row + erow_lane) * KK + k0 + ecol;
        __builtin_amdgcn_global_load_lds(
            (const __attribute__((address_space(1))) void*)gp,
            (__attribute__((address_space(3))) void*)&es[row][0], 16, 0, 0);
      }
#pragma unroll
      for (int r = 0; r < 4; ++r) {
        int tok = xtok + r * 32;
        float4 v = *(const float4*)(x + (size_t)(block_m + tok) * DD + dt + xd4 * 4);
        xs[xd4 * 4 + 0][tok] = v.x;
        xs[xd4 * 4 + 1][tok] = v.y;
        xs[xd4 * 4 + 2][tok] = v.z;
        xs[xd4 * 4 + 3][tok] = v.w;
      }
      __syncthreads();
#pragma unroll 4
      for (int d = 0; d < BD; ++d) {
        const float4 a0 = *(const float4*)&xs[d][wm * 64 + tm * 8];
        const float4 a1 = *(const float4*)&xs[d][wm * 64 + tm * 8 + 4];
        const float4 b0 = *(const float4*)&es[d][wk * 64 + tk * 8];
        const float4 b1 = *(const float4*)&es[d][wk * 64 + tk * 8 + 4];
        const float av[8] = {a0.x, a0.y, a0.z, a0.w, a1.x, a1.y, a1.z, a1.w};
        const float bv[8] = {b0.x, b0.y, b0.z, b0.w, b1.x, b1.y, b1.z, b1.w};
#pragma unroll
        for (int i = 0; i < 8; ++i)
#pragma unroll
          for (int j = 0; j < 8; ++j) acc[i][j] = fmaf(av[i], bv[j], acc[i][j]);
      }
    }
    const int kcol = k0 + wk * 64 + tk * 8;
    float4 h0 = *(const float4*)(he2 + kcol);
    float4 h1 = *(const float4*)(he2 + kcol + 4);
    const float hv[8] = {h0.x, h0.y, h0.z, h0.w, h1.x, h1.y, h1.z, h1.w};
#pragma unroll
    for (int i = 0; i < 8; ++i) {
#pragma unroll
      for (int j = 0; j < 8; ++j) {
        float s = acc[i][j] - hv[j];
        if (s > best[i]) { best[i] = s; bidx[i] = kcol + j; }
      }
    }
  }

  __syncthreads();
  float (*rv)[17] = (float (*)[17])smem;
  int (*ri)[17] = (int (*)[17])(smem + 8704);
#pragma unroll
  for (int i = 0; i < 8; ++i) {
    int tok = wm * 64 + tm * 8 + i;
    rv[tok][wk * 8 + tk] = best[i];
    ri[tok][wk * 8 + tk] = bidx[i];
  }
  __syncthreads();
  if (tid < BM) {
    float bv = rv[tid][0];
    int bi = ri[tid][0];
#pragma unroll
    for (int t = 1; t < 16; ++t) {
      float v = rv[tid][t];
      int ii = ri[tid][t];
      if (v > bv || (v == bv && ii < bi)) { bv = v; bi = ii; }
    }
    uint32_t b = __float_as_uint(bv);
    uint32_t m = (b & 0x80000000u) ? ~b : (b | 0x80000000u);
    unsigned long long packed = ((unsigned long long)m << 32) | (uint32_t)(~(uint32_t)bi);
    atomicMax(&best64[block_m + tid], packed);
  }
}

// ---------------- gather quantized + sum((q-x)^2) + counts ----------------
__global__ __launch_bounds__(256) void gather_et_kernel(
    const float* __restrict__ x, const float* __restrict__ Et,
    const unsigned long long* __restrict__ best64, float* __restrict__ out,
    float* __restrict__ partials, int* __restrict__ counts) {
  __shared__ float sh[256];
  int tid = threadIdx.x;
  int gid = blockIdx.x * 256 + tid;
  int n = gid >> 7;
  int d4 = gid & 127;
  int k = (int)(~(uint32_t)best64[n]);
  float4 q = *(const float4*)(Et + (size_t)k * DD + d4 * 4);
  float4 xv = *(const float4*)(x + (size_t)n * DD + d4 * 4);
  *(float4*)(out + (size_t)n * DD + d4 * 4) = q;
  float dx0 = q.x - xv.x, dx1 = q.y - xv.y, dx2 = q.z - xv.z, dx3 = q.w - xv.w;
  sh[tid] = dx0 * dx0 + dx1 * dx1 + dx2 * dx2 + dx3 * dx3;
  if (d4 == 0) atomicAdd(&counts[k], 1);
  __syncthreads();
  for (int s = 128; s > 0; s >>= 1) {
    if (tid < s) sh[tid] += sh[tid + s];
    __syncthreads();
  }
  if (tid == 0) atomicAdd(&partials[blockIdx.x & 255], sh[0]);
}

__global__ __launch_bounds__(256) void gather_direct_kernel(
    const float* __restrict__ x, const float* __restrict__ E,
    const unsigned long long* __restrict__ best64, float* __restrict__ out,
    float* __restrict__ partials, int* __restrict__ counts) {
  __shared__ float sh[256];
  int tid = threadIdx.x;
  int gid = blockIdx.x * 256 + tid;
  int n = gid >> 7;
  int d4 = gid & 127;
  int k = (int)(~(uint32_t)best64[n]);
  float4 q;
  q.x = E[(size_t)(d4 * 4 + 0) * KK + k];
  q.y = E[(size_t)(d4 * 4 + 1) * KK + k];
  q.z = E[(size_t)(d4 * 4 + 2) * KK + k];
  q.w = E[(size_t)(d4 * 4 + 3) * KK + k];
  float4 xv = *(const float4*)(x + (size_t)n * DD + d4 * 4);
  *(float4*)(out + (size_t)n * DD + d4 * 4) = q;
  float dx0 = q.x - xv.x, dx1 = q.y - xv.y, dx2 = q.z - xv.z, dx3 = q.w - xv.w;
  sh[tid] = dx0 * dx0 + dx1 * dx1 + dx2 * dx2 + dx3 * dx3;
  if (d4 == 0) atomicAdd(&counts[k], 1);
  __syncthreads();
  for (int s = 128; s > 0; s >>= 1) {
    if (tid < s) sh[tid] += sh[tid + s];
    __syncthreads();
  }
  if (tid == 0) atomicAdd(&partials[blockIdx.x & 255], sh[0]);
}

// ---------------- loss + perplexity ----------------
__global__ __launch_bounds__(256) void finalize_kernel(
    const int* __restrict__ counts, const float* __restrict__ partials,
    float* __restrict__ out) {
  __shared__ float sh[256];
  int tid = threadIdx.x;
  float h = 0.f;
  for (int k = tid; k < KK; k += 256) {
    float p = (float)counts[k] * (1.0f / (float)NN);
    h += p * logf(p + 1e-10f);
  }
  sh[tid] = h;
  __syncthreads();
  for (int s = 128; s > 0; s >>= 1) {
    if (tid < s) sh[tid] += sh[tid + s];
    __syncthreads();
  }
  float H = sh[0];
  __syncthreads();
  sh[tid] = partials[tid];
  __syncthreads();
  for (int s = 128; s > 0; s >>= 1) {
    if (tid < s) sh[tid] += sh[tid + s];
    __syncthreads();
  }
  if (tid == 0) {
    float mse = sh[0] / (float)((size_t)NN * DD);
    out[(size_t)NN * DD] = 1.25f * mse;
    out[(size_t)NN * DD + 1] = expf(-H);
  }
}

extern "C" void kernel_launch(void* const* d_in, const int* in_sizes, int n_in,
                              void* d_out, int out_size, void* d_ws, size_t ws_size,
                              hipStream_t stream) {
  const float* x = (const float*)d_in[0];
  const float* E = (const float*)d_in[1];
  float* out = (float*)d_out;
  char* ws = (char*)d_ws;

  // ws layout
  unsigned long long* best64 = (unsigned long long*)(ws + 0);  // 262144
  float* he2 = (float*)(ws + 262144);                          // 16384
  int* counts = (int*)(ws + 278528);                           // 16384
  float* partials = (float*)(ws + 294912);                     // 1024
  unsigned short* Eth = (unsigned short*)(ws + 295936);        // 4 MiB
  float* Et = (float*)(ws + 4490240);                          // 8 MiB (optional)
  const size_t NEED_MFMA = 4490240;
  const size_t NEED_ET = 4490240 + (size_t)DD * KK * 4;

  // zero best64 + he2 + counts + partials
  hipMemsetAsync(ws, 0, 295936, stream);

  if (ws_size >= NEED_MFMA) {
    unsigned short* xh = (unsigned short*)d_out;  // overwritten by gather later
    const bool use_et = ws_size >= NEED_ET;

    if (use_et)
      prep_fused_kernel<true><<<2048 + 8192, 256, 0, stream>>>((const float4*)x, xh, E,
                                                               Eth, he2, Et);
    else
      prep_fused_kernel<false><<<2048 + 8192, 256, 0, stream>>>((const float4*)x, xh, E,
                                                                Eth, he2, Et);
    argmax_mfma_kernel<<<(NN / BMT) * 8, 512, 0, stream>>>(xh, Eth, he2, best64);
    if (use_et)
      gather_et_kernel<<<(NN * (DD / 4)) / 256, 256, 0, stream>>>(x, Et, best64, out,
                                                                  partials, counts);
    else
      gather_direct_kernel<<<(NN * (DD / 4)) / 256, 256, 0, stream>>>(x, E, best64, out,
                                                                      partials, counts);
  } else {
    // fp32 fallback: prep for he2 only (Eth region scratch), then fp32 argmax
    prep_fused_kernel<false><<<2048 + 8192, 256, 0, stream>>>(
        (const float4*)x, (unsigned short*)d_out, E, Eth, he2, (float*)nullptr);
    argmax_kernel<<<(NN / BM) * KS, 256, 0, stream>>>(x, E, he2, best64);
    gather_direct_kernel<<<(NN * (DD / 4)) / 256, 256, 0, stream>>>(x, E, best64, out,
                                                                    partials, counts);
  }
  finalize_kernel<<<1, 256, 0, stream>>>(counts, partials, out);
}

// Round 10
// 314.521 us; speedup vs baseline: 5.5488x; 1.0168x over previous
//
#include <hip/hip_runtime.h>
#include <stdint.h>

#define DD 512
#define KK 4096
#define NN 32768

typedef __attribute__((ext_vector_type(8))) short bf16x8;
typedef __attribute__((ext_vector_type(4))) float f32x4;

__device__ __forceinline__ unsigned short bf16_rn(float f) {
  uint32_t u = __float_as_uint(f);
  return (unsigned short)((u + 0x7FFFu + ((u >> 16) & 1u)) >> 16);
}

__device__ __forceinline__ float bf16_to_f32(unsigned short h) {
  return __uint_as_float((uint32_t)h << 16);
}

// ---- fused prep: blocks [0,2048) do E transpose/bf16/he2; [2048,10240) do x->bf16 ----
// (independent work, one launch; NO cross-block communication -> safe fusion.
//  DO NOT fuse finalize into gather via threadfence/ticket: device-scope fence
//  = per-block L2 writeback on 8 non-coherent XCD L2s -> 35us became 1449us, R7.
//  R10: Et (fp32 transposed copy) dropped entirely — gather reads bf16 Eth instead;
//  saves 64 MB write here + 8MB-random fp32 reads there.)
__global__ __launch_bounds__(256) void prep_fused_kernel(
    const float4* __restrict__ x4, unsigned short* __restrict__ xh,
    const float* __restrict__ E, unsigned short* __restrict__ Eth,
    float* __restrict__ he2) {
  __shared__ float t[32][33];
  const int bid = blockIdx.x;
  if (bid < 2048) {
    // E prep: transpose + bf16 + he2 (wave-shfl reduce, one atomic per (k,wave))
    int bk = (bid & 127) * 32;
    int bd = (bid >> 7) * 32;
    int c = threadIdx.x & 31;
    int r0 = threadIdx.x >> 5;
#pragma unroll
    for (int r = r0; r < 32; r += 8) t[r][c] = E[(size_t)(bd + r) * KK + bk + c];
    __syncthreads();
#pragma unroll
    for (int i = 0; i < 4; ++i) {
      int r = r0 + i * 8;
      float v = t[c][r];  // = E[(bd+c)*KK + bk+r]  (k = bk+r, d = bd+c)
      Eth[(size_t)(bk + r) * DD + bd + c] = bf16_rn(v);
      float v2 = v * v;
#pragma unroll
      for (int m = 1; m < 32; m <<= 1) v2 += __shfl_xor(v2, m, 64);
      if (c == 0) atomicAdd(&he2[bk + r], 0.5f * v2);
    }
  } else {
    // x -> bf16 cast (8 elems/thread)
    int gid = (bid - 2048) * 256 + threadIdx.x;
    float4 a = x4[gid * 2];
    float4 b = x4[gid * 2 + 1];
    union { unsigned short u[8]; uint4 q; } H;
    H.u[0] = bf16_rn(a.x); H.u[1] = bf16_rn(a.y);
    H.u[2] = bf16_rn(a.z); H.u[3] = bf16_rn(a.w);
    H.u[4] = bf16_rn(b.x); H.u[5] = bf16_rn(b.y);
    H.u[6] = bf16_rn(b.z); H.u[7] = bf16_rn(b.w);
    *(uint4*)(xh + (size_t)gid * 8) = H.q;
  }
}

// ---------------- MFMA scores + argmax (single bf16 product) ----------------
// R9 geometry (equal to R8 within noise): BM 256, 512 threads = 8 waves (4x2 grid).
// grid: (NN/256)*8 = 1024, XCD-aware bijective swizzle.
// LDS: dbuf 2 x {A[256][64] 32KB + B[128][64] 16KB} = 96 KB, row stride 128 B,
// XOR-swizzled 16B chunks: slot (row,pos) holds global chunk (pos ^ (row&7)).
// Schedule (R3-proven, DO NOT TOUCH): stage(t+1) into other buf BEFORE compute(t),
// one __syncthreads per step (drains vmcnt + WAR).
// Measured ceiling of this structure: ~178-181us, MfmaUtil ~33% across all of
// {single-buf R2, dbuf R3, counted-vmcnt R5, 2x waves R9} -> m97-structure ceiling;
// escape requires full 8-phase fine interleave (not attempted headless).
// DO NOT: launch_bounds min-waves > 2 [VGPR clamp -> spill, R6]; nt-unroll + hv
// preload [dyn-index scratch, R4]; counted-vmcnt 2-barrier graft [190us, R5].
#define ANB 512
#define BN 128
#define BMT 256

__device__ __forceinline__ void stage_tile2(const unsigned short* __restrict__ xh,
                                            const unsigned short* __restrict__ Eth,
                                            char* Ah, char* Bh, int block_m, int ncode,
                                            int dt, int w, int srow, int schunk) {
  const int col = dt + schunk * 8;
  // A: 256 rows = 8 waves x 4 iters x 8 rows
#pragma unroll
  for (int r = 0; r < 4; ++r) {
    const int rowbase = w * 32 + r * 8;
    const int arow = block_m + rowbase + srow;
    __builtin_amdgcn_global_load_lds(
        (const __attribute__((address_space(1))) void*)(xh + (size_t)arow * DD + col),
        (__attribute__((address_space(3))) void*)(Ah + rowbase * 128), 16, 0, 0);
  }
  // B: 128 rows = 8 waves x 2 iters x 8 rows
#pragma unroll
  for (int r = 0; r < 2; ++r) {
    const int rowbase = w * 16 + r * 8;
    const int brow = ncode + rowbase + srow;
    __builtin_amdgcn_global_load_lds(
        (const __attribute__((address_space(1))) void*)(Eth + (size_t)brow * DD + col),
        (__attribute__((address_space(3))) void*)(Bh + rowbase * 128), 16, 0, 0);
  }
}

__global__ __launch_bounds__(512, 2) void argmax_mfma_kernel(
    const unsigned short* __restrict__ xh, const unsigned short* __restrict__ Eth,
    const float* __restrict__ he2, unsigned long long* __restrict__ best64) {
  __shared__ __align__(16) char smem[98304];  // 2 x {A[256][64] + B[128][64]} bf16

  const int tid = threadIdx.x;
  const int w = tid >> 6;                     // 0..7
  const int lane = tid & 63;
  const int wm = w >> 1, wk = w & 1;          // 4x2 wave grid
  const int l15 = lane & 15, quad = lane >> 4;

  // XCD-aware bijective swizzle: 1024 wgs, 8 XCDs (wg -> XCD = blockIdx%8).
  const int orig = blockIdx.x;
  const int wgid = (orig & 7) * 128 + (orig >> 3);
  const int block_m = (wgid >> 3) * BMT;
  const int nbase = (wgid & 7) * ANB;

  const int srow = lane >> 3;                       // 0..7 row within 8-row group
  const int schunk = (lane & 7) ^ (lane >> 3);      // swizzled source chunk
  const int rx = l15 & 7;                           // frag-read xor key

  float best[16];
  int bidx[16];
#pragma unroll
  for (int s = 0; s < 16; ++s) { best[s] = -INFINITY; bidx[s] = 0; }

  // prologue: stage (nt=0, dt=0) into buf 0
  stage_tile2(xh, Eth, smem, smem + 32768, block_m, nbase, 0, w, srow, schunk);
  __syncthreads();
  int cur = 0;

  for (int nt = 0; nt < 4; ++nt) {
    const int ncode = nbase + nt * BN;
    f32x4 acc[4][4];
#pragma unroll
    for (int ti = 0; ti < 4; ++ti)
#pragma unroll
      for (int tj = 0; tj < 4; ++tj) acc[ti][tj] = (f32x4){0.f, 0.f, 0.f, 0.f};

    for (int dtI = 0; dtI < 8; ++dtI) {
      // issue next tile's loads early (into the other buffer)
      char* nAh = smem + (cur ^ 1) * 49152;
      if (dtI < 7) {
        stage_tile2(xh, Eth, nAh, nAh + 32768, block_m, ncode, (dtI + 1) * 64, w, srow,
                    schunk);
      } else if (nt < 3) {
        stage_tile2(xh, Eth, nAh, nAh + 32768, block_m, ncode + BN, 0, w, srow, schunk);
      }

      // compute current buffer
      char* Ah = smem + cur * 49152;
      char* Bh = Ah + 32768;
#pragma unroll
      for (int s = 0; s < 2; ++s) {
        const int ch = ((s * 4 + quad) ^ rx) * 16;
        bf16x8 af[4], bfv[4];
#pragma unroll
        for (int t = 0; t < 4; ++t) {
          af[t] = *(const bf16x8*)(Ah + (wm * 64 + t * 16 + l15) * 128 + ch);
          bfv[t] = *(const bf16x8*)(Bh + (wk * 64 + t * 16 + l15) * 128 + ch);
        }
#pragma unroll
        for (int ti = 0; ti < 4; ++ti)
#pragma unroll
          for (int tj = 0; tj < 4; ++tj)
            acc[ti][tj] = __builtin_amdgcn_mfma_f32_16x16x32_bf16(af[ti], bfv[tj],
                                                                  acc[ti][tj], 0, 0, 0);
      }
      __syncthreads();  // drains next-tile vmcnt (post-compute) + cross-wave barrier
      cur ^= 1;
    }

    // fold this 128-code tile: score = dot - 0.5|e|^2
    const int colb = ncode + wk * 64 + l15;
#pragma unroll
    for (int tj = 0; tj < 4; ++tj) {
      float h = he2[colb + tj * 16];
#pragma unroll
      for (int ti = 0; ti < 4; ++ti)
#pragma unroll
        for (int r = 0; r < 4; ++r) {
          float sc = acc[ti][tj][r] - h;
          int slot = ti * 4 + r;
          if (sc > best[slot]) { best[slot] = sc; bidx[slot] = colb + tj * 16; }
        }
    }
  }

  // reduce over the 16 col-lanes per row group, then cross-block atomicMax
#pragma unroll
  for (int slot = 0; slot < 16; ++slot) {
    float v = best[slot];
    int ii = bidx[slot];
#pragma unroll
    for (int m = 1; m < 16; m <<= 1) {
      float ov = __shfl_xor(v, m, 64);
      int oi = __shfl_xor(ii, m, 64);
      if (ov > v || (ov == v && oi < ii)) { v = ov; ii = oi; }
    }
    if (l15 == 0) {
      int row = block_m + wm * 64 + (slot >> 2) * 16 + quad * 4 + (slot & 3);
      uint32_t b = __float_as_uint(v);
      uint32_t mm = (b & 0x80000000u) ? ~b : (b | 0x80000000u);
      unsigned long long packed = ((unsigned long long)mm << 32) | (uint32_t)(~(uint32_t)ii);
      atomicMax(&best64[row], packed);
    }
  }
}

// ---------------- fallback fp32 argmax (used when ws too small) ----------------
#define BM 128
#define BK 128
#define KS 4
#define KPB (KK / KS)
#define BD 32

__global__ __launch_bounds__(256, 4) void argmax_kernel(
    const float* __restrict__ x, const float* __restrict__ E,
    const float* __restrict__ he2, unsigned long long* __restrict__ best64) {
  __shared__ __align__(16) char smem[33280];
  float (*xs)[132] = (float (*)[132])smem;
  float (*es)[BK] = (float (*)[BK])(smem + 16896);

  const int tid = threadIdx.x;
  const int wave = tid >> 6;
  const int lane = tid & 63;
  const int wm = wave >> 1, wk = wave & 1;
  const int tm = lane >> 3, tk = lane & 7;
  const int block_m = (blockIdx.x >> 2) * BM;
  const int kbase = (blockIdx.x & 3) * KPB;

  float best[8];
  int bidx[8];
#pragma unroll
  for (int i = 0; i < 8; ++i) { best[i] = -INFINITY; bidx[i] = 0; }

  const int xtok = tid >> 3;
  const int xd4 = tid & 7;
  const int erow_lane = (lane >> 5);
  const int ecol = (lane & 31) * 4;

  for (int kt = 0; kt < KPB; kt += BK) {
    const int k0 = kbase + kt;
    float acc[8][8];
#pragma unroll
    for (int i = 0; i < 8; ++i)
#pragma unroll
      for (int j = 0; j < 8; ++j) acc[i][j] = 0.f;

    for (int dt = 0; dt < DD; dt += BD) {
      __syncthreads();
#pragma unroll
      for (int r = 0; r < 4; ++r) {
        int row = r * 8 + wave * 2;
        const float* gp = E + (size_t)(dt + row + erow_lane) * KK + k0 + ecol;
        __builtin_amdgcn_global_load_lds(
            (const __attribute__((address_space(1))) void*)gp,
            (__attribute__((address_space(3))) void*)&es[row][0], 16, 0, 0);
      }
#pragma unroll
      for (int r = 0; r < 4; ++r) {
        int tok = xtok + r * 32;
        float4 v = *(const float4*)(x + (size_t)(block_m + tok) * DD + dt + xd4 * 4);
        xs[xd4 * 4 + 0][tok] = v.x;
        xs[xd4 * 4 + 1][tok] = v.y;
        xs[xd4 * 4 + 2][tok] = v.z;
        xs[xd4 * 4 + 3][tok] = v.w;
      }
      __syncthreads();
#pragma unroll 4
      for (int d = 0; d < BD; ++d) {
        const float4 a0 = *(const float4*)&xs[d][wm * 64 + tm * 8];
        const float4 a1 = *(const float4*)&xs[d][wm * 64 + tm * 8 + 4];
        const float4 b0 = *(const float4*)&es[d][wk * 64 + tk * 8];
        const float4 b1 = *(const float4*)&es[d][wk * 64 + tk * 8 + 4];
        const float av[8] = {a0.x, a0.y, a0.z, a0.w, a1.x, a1.y, a1.z, a1.w};
        const float bv[8] = {b0.x, b0.y, b0.z, b0.w, b1.x, b1.y, b1.z, b1.w};
#pragma unroll
        for (int i = 0; i < 8; ++i)
#pragma unroll
          for (int j = 0; j < 8; ++j) acc[i][j] = fmaf(av[i], bv[j], acc[i][j]);
      }
    }
    const int kcol = k0 + wk * 64 + tk * 8;
    float4 h0 = *(const float4*)(he2 + kcol);
    float4 h1 = *(const float4*)(he2 + kcol + 4);
    const float hv[8] = {h0.x, h0.y, h0.z, h0.w, h1.x, h1.y, h1.z, h1.w};
#pragma unroll
    for (int i = 0; i < 8; ++i) {
#pragma unroll
      for (int j = 0; j < 8; ++j) {
        float s = acc[i][j] - hv[j];
        if (s > best[i]) { best[i] = s; bidx[i] = kcol + j; }
      }
    }
  }

  __syncthreads();
  float (*rv)[17] = (float (*)[17])smem;
  int (*ri)[17] = (int (*)[17])(smem + 8704);
#pragma unroll
  for (int i = 0; i < 8; ++i) {
    int tok = wm * 64 + tm * 8 + i;
    rv[tok][wk * 8 + tk] = best[i];
    ri[tok][wk * 8 + tk] = bidx[i];
  }
  __syncthreads();
  if (tid < BM) {
    float bv = rv[tid][0];
    int bi = ri[tid][0];
#pragma unroll
    for (int t = 1; t < 16; ++t) {
      float v = rv[tid][t];
      int ii = ri[tid][t];
      if (v > bv || (v == bv && ii < bi)) { bv = v; bi = ii; }
    }
    uint32_t b = __float_as_uint(bv);
    uint32_t m = (b & 0x80000000u) ? ~b : (b | 0x80000000u);
    unsigned long long packed = ((unsigned long long)m << 32) | (uint32_t)(~(uint32_t)bi);
    atomicMax(&best64[block_m + tid], packed);
  }
}

// ---- gather quantized from bf16 Eth (4 MB, L2-resident) + sum((q-x)^2) + counts ----
__global__ __launch_bounds__(256) void gather_eth_kernel(
    const float* __restrict__ x, const unsigned short* __restrict__ Eth,
    const unsigned long long* __restrict__ best64, float* __restrict__ out,
    float* __restrict__ partials, int* __restrict__ counts) {
  __shared__ float sh[256];
  int tid = threadIdx.x;
  int gid = blockIdx.x * 256 + tid;
  int n = gid >> 7;
  int d4 = gid & 127;
  int k = (int)(~(uint32_t)best64[n]);
  ushort4 qh = *(const ushort4*)(Eth + (size_t)k * DD + d4 * 4);
  float4 q;
  q.x = bf16_to_f32(qh.x);
  q.y = bf16_to_f32(qh.y);
  q.z = bf16_to_f32(qh.z);
  q.w = bf16_to_f32(qh.w);
  float4 xv = *(const float4*)(x + (size_t)n * DD + d4 * 4);
  *(float4*)(out + (size_t)n * DD + d4 * 4) = q;
  float dx0 = q.x - xv.x, dx1 = q.y - xv.y, dx2 = q.z - xv.z, dx3 = q.w - xv.w;
  sh[tid] = dx0 * dx0 + dx1 * dx1 + dx2 * dx2 + dx3 * dx3;
  if (d4 == 0) atomicAdd(&counts[k], 1);
  __syncthreads();
  for (int s = 128; s > 0; s >>= 1) {
    if (tid < s) sh[tid] += sh[tid + s];
    __syncthreads();
  }
  if (tid == 0) atomicAdd(&partials[blockIdx.x & 255], sh[0]);
}

__global__ __launch_bounds__(256) void gather_direct_kernel(
    const float* __restrict__ x, const float* __restrict__ E,
    const unsigned long long* __restrict__ best64, float* __restrict__ out,
    float* __restrict__ partials, int* __restrict__ counts) {
  __shared__ float sh[256];
  int tid = threadIdx.x;
  int gid = blockIdx.x * 256 + tid;
  int n = gid >> 7;
  int d4 = gid & 127;
  int k = (int)(~(uint32_t)best64[n]);
  float4 q;
  q.x = E[(size_t)(d4 * 4 + 0) * KK + k];
  q.y = E[(size_t)(d4 * 4 + 1) * KK + k];
  q.z = E[(size_t)(d4 * 4 + 2) * KK + k];
  q.w = E[(size_t)(d4 * 4 + 3) * KK + k];
  float4 xv = *(const float4*)(x + (size_t)n * DD + d4 * 4);
  *(float4*)(out + (size_t)n * DD + d4 * 4) = q;
  float dx0 = q.x - xv.x, dx1 = q.y - xv.y, dx2 = q.z - xv.z, dx3 = q.w - xv.w;
  sh[tid] = dx0 * dx0 + dx1 * dx1 + dx2 * dx2 + dx3 * dx3;
  if (d4 == 0) atomicAdd(&counts[k], 1);
  __syncthreads();
  for (int s = 128; s > 0; s >>= 1) {
    if (tid < s) sh[tid] += sh[tid + s];
    __syncthreads();
  }
  if (tid == 0) atomicAdd(&partials[blockIdx.x & 255], sh[0]);
}

// ---------------- loss + perplexity ----------------
__global__ __launch_bounds__(256) void finalize_kernel(
    const int* __restrict__ counts, const float* __restrict__ partials,
    float* __restrict__ out) {
  __shared__ float sh[256];
  int tid = threadIdx.x;
  float h = 0.f;
  for (int k = tid; k < KK; k += 256) {
    float p = (float)counts[k] * (1.0f / (float)NN);
    h += p * logf(p + 1e-10f);
  }
  sh[tid] = h;
  __syncthreads();
  for (int s = 128; s > 0; s >>= 1) {
    if (tid < s) sh[tid] += sh[tid + s];
    __syncthreads();
  }
  float H = sh[0];
  __syncthreads();
  sh[tid] = partials[tid];
  __syncthreads();
  for (int s = 128; s > 0; s >>= 1) {
    if (tid < s) sh[tid] += sh[tid + s];
    __syncthreads();
  }
  if (tid == 0) {
    float mse = sh[0] / (float)((size_t)NN * DD);
    out[(size_t)NN * DD] = 1.25f * mse;
    out[(size_t)NN * DD + 1] = expf(-H);
  }
}

extern "C" void kernel_launch(void* const* d_in, const int* in_sizes, int n_in,
                              void* d_out, int out_size, void* d_ws, size_t ws_size,
                              hipStream_t stream) {
  const float* x = (const float*)d_in[0];
  const float* E = (const float*)d_in[1];
  float* out = (float*)d_out;
  char* ws = (char*)d_ws;

  // ws layout
  unsigned long long* best64 = (unsigned long long*)(ws + 0);  // 262144
  float* he2 = (float*)(ws + 262144);                          // 16384
  int* counts = (int*)(ws + 278528);                           // 16384
  float* partials = (float*)(ws + 294912);                     // 1024
  unsigned short* Eth = (unsigned short*)(ws + 295936);        // 4 MiB
  const size_t NEED_MFMA = 4490240;

  // zero best64 + he2 + counts + partials
  hipMemsetAsync(ws, 0, 295936, stream);

  if (ws_size >= NEED_MFMA) {
    unsigned short* xh = (unsigned short*)d_out;  // overwritten by gather later

    prep_fused_kernel<<<2048 + 8192, 256, 0, stream>>>((const float4*)x, xh, E, Eth,
                                                       he2);
    argmax_mfma_kernel<<<(NN / BMT) * 8, 512, 0, stream>>>(xh, Eth, he2, best64);
    gather_eth_kernel<<<(NN * (DD / 4)) / 256, 256, 0, stream>>>(x, Eth, best64, out,
                                                                 partials, counts);
  } else {
    // fp32 fallback: prep for he2 only (Eth region scratch), then fp32 argmax
    prep_fused_kernel<<<2048 + 8192, 256, 0, stream>>>(
        (const float4*)x, (unsigned short*)d_out, E, Eth, he2);
    argmax_kernel<<<(NN / BM) * KS, 256, 0, stream>>>(x, E, he2, best64);
    gather_direct_kernel<<<(NN * (DD / 4)) / 256, 256, 0, stream>>>(x, E, best64, out,
                                                                    partials, counts);
  }
  finalize_kernel<<<1, 256, 0, stream>>>(counts, partials, out);
}